// Round 1
// baseline (1255.570 us; speedup 1.0000x reference)
//
#include <hip/hip_runtime.h>

typedef __bf16 bf16;
typedef __bf16 bf16x4 __attribute__((ext_vector_type(4)));
typedef __bf16 bf16x8 __attribute__((ext_vector_type(8)));
typedef float f32x4 __attribute__((ext_vector_type(4)));

#define N_NODES 1568
#define CDIM 2048

// ---------------- async global->LDS 16B ----------------
__device__ __forceinline__ void async_copy16(const bf16* g, bf16* l) {
    __builtin_amdgcn_global_load_lds(
        (const __attribute__((address_space(1))) unsigned int*)g,
        (__attribute__((address_space(3))) unsigned int*)l, 16, 0, 0);
}

// ---------------- generic NT bf16 MFMA GEMM ----------------
// C[M,N] = A[M,K] * B[N,K]^T ; lda=ldb=K, ldc=N. Batched via grid.z with strides.
// launch_bounds(256,2): cap 256 VGPR so the allocator can hoist addresses
// (bare (256) squeezed to 64 VGPR -> VALU-bound address recompute, R2 evidence)
template <typename OUT_T>
__global__ __launch_bounds__(256, 2) void gemm_nt(const bf16* __restrict__ A,
                                                  const bf16* __restrict__ B,
                                                  OUT_T* __restrict__ C,
                                                  int M, int N, int K,
                                                  long sAb, long sBb, long sCb) {
    __shared__ __align__(16) bf16 sA[128 * 32];
    __shared__ __align__(16) bf16 sB[128 * 32];
    const int bz = blockIdx.z;
    A += (long)bz * sAb; B += (long)bz * sBb; C += (long)bz * sCb;
    const int m0 = blockIdx.x * 128, n0 = blockIdx.y * 128;
    const int t = threadIdx.x;
    const int lane = t & 63, wave = t >> 6;
    const int wr = wave >> 1, wc = wave & 1;
    const int l15 = lane & 15, quad = lane >> 4;

    f32x4 acc[4][4];
#pragma unroll
    for (int i = 0; i < 4; i++)
#pragma unroll
        for (int j = 0; j < 4; j++) acc[i][j] = (f32x4){0.f, 0.f, 0.f, 0.f};

    const int ko = (t & 3) * 8;
    int ra1 = m0 + (t >> 2);          if (ra1 >= M) ra1 = M - 1;
    int ra2 = m0 + ((t + 256) >> 2);  if (ra2 >= M) ra2 = M - 1;
    int rb1 = n0 + (t >> 2);          if (rb1 >= N) rb1 = N - 1;
    int rb2 = n0 + ((t + 256) >> 2);  if (rb2 >= N) rb2 = N - 1;
    const bf16* gA1 = A + (long)ra1 * K + ko;
    const bf16* gA2 = A + (long)ra2 * K + ko;
    const bf16* gB1 = B + (long)rb1 * K + ko;
    const bf16* gB2 = B + (long)rb2 * K + ko;
    bf16* lA1 = sA + t * 8;  bf16* lA2 = sA + (t + 256) * 8;
    bf16* lB1 = sB + t * 8;  bf16* lB2 = sB + (t + 256) * 8;

    for (int k0 = 0; k0 < K; k0 += 32) {
        __syncthreads();
        async_copy16(gA1 + k0, lA1);
        async_copy16(gA2 + k0, lA2);
        async_copy16(gB1 + k0, lB1);
        async_copy16(gB2 + k0, lB2);
        __syncthreads();
        bf16x8 af[4], bfr[4];
#pragma unroll
        for (int i = 0; i < 4; i++)
            af[i] = *(const bf16x8*)(sA + (wr * 64 + i * 16 + l15) * 32 + quad * 8);
#pragma unroll
        for (int j = 0; j < 4; j++)
            bfr[j] = *(const bf16x8*)(sB + (wc * 64 + j * 16 + l15) * 32 + quad * 8);
#pragma unroll
        for (int i = 0; i < 4; i++)
#pragma unroll
            for (int j = 0; j < 4; j++)
                acc[i][j] = __builtin_amdgcn_mfma_f32_16x16x32_bf16(af[i], bfr[j], acc[i][j], 0, 0, 0);
    }
    // epilogue: D[row=quad*4+r][col=l15] per 16x16 tile (m89-verified layout)
#pragma unroll
    for (int i = 0; i < 4; i++) {
        const int row0 = m0 + wr * 64 + i * 16 + quad * 4;
#pragma unroll
        for (int j = 0; j < 4; j++) {
            const int col = n0 + wc * 64 + j * 16 + l15;
            if (col < N) {
#pragma unroll
                for (int r = 0; r < 4; r++) {
                    const int row = row0 + r;
                    if (row < M) C[(long)row * N + col] = (OUT_T)acc[i][j][r];
                }
            }
        }
    }
}

// ---------------- symmetric NT GEMM: C = A A^T (f32 out) ----------------
// Only upper-triangle tiles computed (linear grid.x over 91 tiles), mirrored
// into the lower triangle in the epilogue. M == N.
__global__ __launch_bounds__(256, 2) void gemm_nt_sym(const bf16* __restrict__ A,
                                                      float* __restrict__ C,
                                                      int M, int K,
                                                      long sAb, long sCb) {
    __shared__ __align__(16) bf16 sA[128 * 32];
    __shared__ __align__(16) bf16 sB[128 * 32];
    const int bz = blockIdx.z;
    A += (long)bz * sAb; C += (long)bz * sCb;
    // decode triangular tile id -> (bi, bj), bj >= bi, 13 tiles per side
    int rem = blockIdx.x, bi = 0;
    while (rem >= 13 - bi) { rem -= 13 - bi; bi++; }
    const int bj = bi + rem;
    const int m0 = bi * 128, n0 = bj * 128;
    const int t = threadIdx.x;
    const int lane = t & 63, wave = t >> 6;
    const int wr = wave >> 1, wc = wave & 1;
    const int l15 = lane & 15, quad = lane >> 4;

    f32x4 acc[4][4];
#pragma unroll
    for (int i = 0; i < 4; i++)
#pragma unroll
        for (int j = 0; j < 4; j++) acc[i][j] = (f32x4){0.f, 0.f, 0.f, 0.f};

    const int ko = (t & 3) * 8;
    int ra1 = m0 + (t >> 2);          if (ra1 >= M) ra1 = M - 1;
    int ra2 = m0 + ((t + 256) >> 2);  if (ra2 >= M) ra2 = M - 1;
    int rb1 = n0 + (t >> 2);          if (rb1 >= M) rb1 = M - 1;
    int rb2 = n0 + ((t + 256) >> 2);  if (rb2 >= M) rb2 = M - 1;
    const bf16* gA1 = A + (long)ra1 * K + ko;
    const bf16* gA2 = A + (long)ra2 * K + ko;
    const bf16* gB1 = A + (long)rb1 * K + ko;
    const bf16* gB2 = A + (long)rb2 * K + ko;
    bf16* lA1 = sA + t * 8;  bf16* lA2 = sA + (t + 256) * 8;
    bf16* lB1 = sB + t * 8;  bf16* lB2 = sB + (t + 256) * 8;

    for (int k0 = 0; k0 < K; k0 += 32) {
        __syncthreads();
        async_copy16(gA1 + k0, lA1);
        async_copy16(gA2 + k0, lA2);
        async_copy16(gB1 + k0, lB1);
        async_copy16(gB2 + k0, lB2);
        __syncthreads();
        bf16x8 af[4], bfr[4];
#pragma unroll
        for (int i = 0; i < 4; i++)
            af[i] = *(const bf16x8*)(sA + (wr * 64 + i * 16 + l15) * 32 + quad * 8);
#pragma unroll
        for (int j = 0; j < 4; j++)
            bfr[j] = *(const bf16x8*)(sB + (wc * 64 + j * 16 + l15) * 32 + quad * 8);
#pragma unroll
        for (int i = 0; i < 4; i++)
#pragma unroll
            for (int j = 0; j < 4; j++)
                acc[i][j] = __builtin_amdgcn_mfma_f32_16x16x32_bf16(af[i], bfr[j], acc[i][j], 0, 0, 0);
    }
    const bool mirror = (bi != bj);
#pragma unroll
    for (int i = 0; i < 4; i++) {
        const int row0 = m0 + wr * 64 + i * 16 + quad * 4;
#pragma unroll
        for (int j = 0; j < 4; j++) {
            const int col = n0 + wc * 64 + j * 16 + l15;
            if (col < M) {
#pragma unroll
                for (int r = 0; r < 4; r++) {
                    const int row = row0 + r;
                    if (row < M) {
                        const float v = acc[i][j][r];
                        C[(long)row * M + col] = v;
                        if (mirror) C[(long)col * M + row] = v;
                    }
                }
            }
        }
    }
}

// ---------------- f32 -> bf16 cast (vectorized) ----------------
__global__ __launch_bounds__(256) void cast_f32_bf16_k(const float* __restrict__ in,
                                                       bf16* __restrict__ out, long n) {
    long i = ((long)blockIdx.x * 256 + threadIdx.x) * 4;
    if (i >= n) return;
    float4 v = *(const float4*)(in + i);
    bf16x4 o;
    o[0] = (bf16)v.x; o[1] = (bf16)v.y; o[2] = (bf16)v.z; o[3] = (bf16)v.w;
    *(bf16x4*)(out + i) = o;
}

// 4 equal-size weight matrices in one launch (blockIdx.y selects)
__global__ __launch_bounds__(256) void cast4_f32_bf16_k(const float* __restrict__ a,
                                                        const float* __restrict__ b,
                                                        const float* __restrict__ c,
                                                        const float* __restrict__ d,
                                                        bf16* __restrict__ out, long n) {
    const int w = blockIdx.y;
    const float* in = (w == 0) ? a : (w == 1) ? b : (w == 2) ? c : d;
    bf16* o = out + (long)w * n;
    long i = ((long)blockIdx.x * 256 + threadIdx.x) * 4;
    if (i >= n) return;
    float4 v = *(const float4*)(in + i);
    bf16x4 ov;
    ov[0] = (bf16)v.x; ov[1] = (bf16)v.y; ov[2] = (bf16)v.z; ov[3] = (bf16)v.w;
    *(bf16x4*)(o + i) = ov;
}

// ---------------- bf16 tiled transpose (batched) ----------------
__global__ __launch_bounds__(256) void transpose_bf16_k(const bf16* __restrict__ in,
                                                        bf16* __restrict__ out,
                                                        int R, int C, long sIn, long sOut) {
    __shared__ bf16 tile[64][65];
    in += (long)blockIdx.z * sIn;
    out += (long)blockIdx.z * sOut;
    const int r0 = blockIdx.y * 64, c0 = blockIdx.x * 64;
    const int tx = threadIdx.x & 63, ty = threadIdx.x >> 6;
#pragma unroll
    for (int i = 0; i < 16; i++) {
        int r = ty * 16 + i;
        int gr = r0 + r, gc = c0 + tx;
        tile[r][tx] = (gr < R && gc < C) ? in[(long)gr * C + gc] : (bf16)0.f;
    }
    __syncthreads();
#pragma unroll
    for (int i = 0; i < 16; i++) {
        int c = ty * 16 + i;
        int gc = c0 + c, gr = r0 + tx;
        if (gc < C && gr < R) out[(long)gc * R + gr] = tile[tx][c];
    }
}

// ---------------- adjacency: column sums of s^2 (partials + combine) ----------------
__global__ __launch_bounds__(256) void colsum_part_k(const float* __restrict__ s,
                                                     float* __restrict__ part) {
    int m = blockIdx.x * 256 + threadIdx.x;
    if (m >= N_NODES) return;
    int y = blockIdx.y, b = blockIdx.z;
    const float* sb = s + (long)b * N_NODES * N_NODES;
    float acc = 0.f;
    for (int n = y * 196; n < y * 196 + 196; ++n) {
        float v = sb[(long)n * N_NODES + m];
        acc += v * v;
    }
    part[((long)y * 4 + b) * N_NODES + m] = acc;
}

__global__ __launch_bounds__(256) void colsum_comb_k(const float* __restrict__ part,
                                                     float* __restrict__ inv) {
    int m = blockIdx.x * 256 + threadIdx.x;
    if (m >= N_NODES) return;
    int b = blockIdx.y;
    float a = 0.f;
#pragma unroll
    for (int y = 0; y < 8; y++) a += part[((long)y * 4 + b) * N_NODES + m];
    inv[(long)b * N_NODES + m] = 1.0f / a;
}

// lap[n,m] = 0.5 * s^2[n,m] * inv[m] + 0.5*(n==m)   (d == 1/sqrt(2) exactly)
__global__ __launch_bounds__(256) void lap_build_k(const float* __restrict__ s,
                                                   const float* __restrict__ inv,
                                                   bf16* __restrict__ lap) {
    int m = blockIdx.x * 256 + threadIdx.x;
    if (m >= N_NODES) return;
    int n = blockIdx.y, b = blockIdx.z;
    long off = (long)b * N_NODES * N_NODES + (long)n * N_NODES + m;
    float v = s[off];
    float l = 0.5f * v * v * inv[(long)b * N_NODES + m];
    if (n == m) l += 0.5f;
    lap[off] = (bf16)l;
}

// ---------------- LayerNorm(2048) + LeakyReLU(0.1), row-per-block ----------------
__global__ __launch_bounds__(256) void ln_leaky_k(const float* __restrict__ y,
                                                  const float* __restrict__ g,
                                                  const float* __restrict__ beta,
                                                  bf16* __restrict__ z) {
    const long row = blockIdx.x;
    const float* yr = y + row * CDIM;
    const int t = threadIdx.x;
    float v[8];
    float s = 0.f, ss = 0.f;
#pragma unroll
    for (int i = 0; i < 8; i++) {
        float x = yr[t + 256 * i];
        v[i] = x; s += x; ss += x * x;
    }
#pragma unroll
    for (int o = 32; o > 0; o >>= 1) {
        s += __shfl_down(s, o);
        ss += __shfl_down(ss, o);
    }
    __shared__ float sh[8];
    const int wave = t >> 6;
    if ((t & 63) == 0) { sh[wave] = s; sh[wave + 4] = ss; }
    __syncthreads();
    if (t == 0) {
        float a = 0.f, b2 = 0.f;
#pragma unroll
        for (int w = 0; w < 4; w++) { a += sh[w]; b2 += sh[w + 4]; }
        sh[0] = a; sh[4] = b2;
    }
    __syncthreads();
    const float mean = sh[0] * (1.f / 2048.f);
    const float var = sh[4] * (1.f / 2048.f) - mean * mean;
    const float invs = rsqrtf(var + 1e-5f);
    bf16* zr = z + row * CDIM;
#pragma unroll
    for (int i = 0; i < 8; i++) {
        int c = t + 256 * i;
        float o = (v[i] - mean) * invs * g[c] + beta[c];
        o = o > 0.f ? o : 0.1f * o;
        zr[c] = (bf16)o;
    }
}

// ---------------- head: conv1 over 8 frame channels ----------------
__global__ __launch_bounds__(256) void conv1_k(const bf16* __restrict__ z,
                                               const float* __restrict__ cw,
                                               const float* __restrict__ cb,
                                               bf16* __restrict__ tb) {
    const int b = blockIdx.z, hw = blockIdx.y;
    const int c = blockIdx.x * 256 + threadIdx.x;
    float acc = cb[0];
#pragma unroll
    for (int f = 0; f < 8; f++)
        acc += (float)z[((long)b * N_NODES + f * 196 + hw) * CDIM + c] * cw[f];
    tb[((long)b * 196 + hw) * CDIM + c] = (bf16)acc;
}

// ---------------- bilinear x2 upsample, half-pixel, edge clamp ----------------
__global__ __launch_bounds__(256) void upsample_k(const bf16* __restrict__ tb,
                                                  bf16* __restrict__ u) {
    const int b = blockIdx.z, i = blockIdx.y, j = blockIdx.x;
    const float si = 0.5f * i - 0.25f, sj = 0.5f * j - 0.25f;
    const int i0 = (int)floorf(si), j0 = (int)floorf(sj);
    const float wi = si - i0, wj = sj - j0;
    const int i0c = max(i0, 0), i1c = min(i0 + 1, 13);
    const int j0c = max(j0, 0), j1c = min(j0 + 1, 13);
    const bf16* base = tb + (long)b * 196 * CDIM;
    const long r00 = ((long)i0c * 14 + j0c) * CDIM, r01 = ((long)i0c * 14 + j1c) * CDIM;
    const long r10 = ((long)i1c * 14 + j0c) * CDIM, r11 = ((long)i1c * 14 + j1c) * CDIM;
    bf16* ur = u + ((long)(b * 28 + i) * 28 + j) * CDIM;
    const float w00 = (1.f - wi) * (1.f - wj), w01 = (1.f - wi) * wj;
    const float w10 = wi * (1.f - wj), w11 = wi * wj;
    for (int k = 0; k < 8; k++) {
        int cc = threadIdx.x + 256 * k;
        float v = w00 * (float)base[r00 + cc] + w01 * (float)base[r01 + cc] +
                  w10 * (float)base[r10 + cc] + w11 * (float)base[r11 + cc];
        ur[cc] = (bf16)v;
    }
}

// ---------------- deconv weight transform ----------------
__global__ __launch_bounds__(256) void wt_k(const float* __restrict__ dw,
                                            bf16* __restrict__ Wt) {
    const int ic = blockIdx.x * 256 + threadIdx.x;
    const int oc = blockIdx.y;
    const float* src = dw + ((long)ic * 1024 + oc) * 9;
#pragma unroll
    for (int r = 0; r < 3; r++)
#pragma unroll
        for (int s = 0; s < 3; s++) {
            int kh = 2 - r, kw = 2 - s;
            Wt[((long)(kh * 3 + kw) * 1024 + oc) * 2048 + ic] = (bf16)src[r * 3 + s];
        }
}

// ---------------- deconv scatter: r[g*1024+oc][b*784+p] (bf16) -> out[b][oc][82][82] ----------------
__global__ __launch_bounds__(256) void deconv_scatter_k(const bf16* __restrict__ r,
                                                        const float* __restrict__ db,
                                                        float* __restrict__ out) {
    const int blk = blockIdx.x;          // 4096 = b*1024 + oc
    const int b = blk >> 10, oc = blk & 1023;
    const float bias = db[oc];
    float* ob = out + (long)blk * 82 * 82;
    for (int e = threadIdx.x; e < 82 * 82; e += 256) {
        const int oh = e / 82, ow = e - oh * 82;
        const int mh = oh % 3, mw = ow % 3;
        const int kh = (mh == 0) ? 1 : ((mh == 1) ? 0 : 2);
        const int kw = (mw == 0) ? 1 : ((mw == 1) ? 0 : 2);
        const int ih = (oh - (1 - kh)) / 3;
        const int iw = (ow - (1 - kw)) / 3;
        const int g = kh * 3 + kw;
        ob[e] = (float)r[(long)(g * 1024 + oc) * 3136 + b * 784 + ih * 28 + iw] + bias;
    }
}

// =====================================================================
extern "C" void kernel_launch(void* const* d_in, const int* in_sizes, int n_in,
                              void* d_out, int out_size, void* d_ws, size_t ws_size,
                              hipStream_t stream) {
    const float* x        = (const float*)d_in[0];
    const float* w_fc1    = (const float*)d_in[1];
    const float* w1       = (const float*)d_in[2];
    const float* g1       = (const float*)d_in[3];
    const float* b1       = (const float*)d_in[4];
    const float* w2       = (const float*)d_in[5];
    const float* g2       = (const float*)d_in[6];
    const float* b2       = (const float*)d_in[7];
    const float* w3       = (const float*)d_in[8];
    const float* g3       = (const float*)d_in[9];
    const float* b3       = (const float*)d_in[10];
    const float* conv1_w  = (const float*)d_in[11];
    const float* conv1_b  = (const float*)d_in[12];
    const float* deconv_w = (const float*)d_in[13];
    const float* deconv_b = (const float*)d_in[14];
    float* out = (float*)d_out;

    // ---- workspace layout (bytes) ----
    char* W = (char*)d_ws;
    bf16* wb   = (bf16*)(W + 0);            // 4 x 2048x2048 bf16 = 33,554,432
    bf16* xb   = (bf16*)(W + 33554432);     // 6272x2048 bf16 (later: z)
    bf16* xbT  = (bf16*)(W + 59244544);     // 4 x 2048x1568 bf16 (later: zT)
    bf16* hb   = (bf16*)(W + 84934656);     // 6272x2048 bf16 (later: outN)
    bf16* lap  = (bf16*)(W + 110624768);    // 4 x 1568x1568 bf16 = 19,668,992
    bf16* tbuf = (bf16*)(W + 130293760);    // 4 x 196x2048 bf16 = 3,211,264
    bf16* ubuf = (bf16*)(W + 133505024);    // 4 x 784x2048 bf16 = 12,845,056
    bf16* Wt   = (bf16*)(W + 146350080);    // 9 x 1024x2048 bf16 = 37,748,736
    float* ybuf = (float*)(W + 184098816);  // 6272x2048 f32 = 51,380,224
    float* sbuf = (float*)(W + 184098816);  // s overlays y (dead before first y write)
    float* part = (float*)(W + 235479040);  // 8x4x1568 f32
    float* invc = (float*)(W + 235679744);  // 4x1568 f32
    // rbuf (bf16 now) overlays wb/xb region: dead by deconv time
    bf16* rbuf = (bf16*)(W + 0);            // 9216 x 3136 bf16 = 57,802,752
    bf16* zb = xb;    // reuse (xb dead after fc1 + transpose)
    bf16* zT = xbT;   // reuse
    bf16* outN = hb;  // reuse (hb dead after s GEMM)

    const long WMAT = (long)2048 * 2048;
    bf16* wb0 = wb, *wb1 = wb + WMAT, *wb2 = wb + 2 * WMAT, *wb3 = wb + 3 * WMAT;

    // ---- weight / input casts ----
    cast4_f32_bf16_k<<<dim3(4096, 4), 256, 0, stream>>>(w_fc1, w1, w2, w3, wb, WMAT);
    cast_f32_bf16_k<<<dim3(12544), 256, 0, stream>>>(x, xb, (long)6272 * 2048);
    wt_k<<<dim3(8, 1024), 256, 0, stream>>>(deconv_w, Wt);

    // xbT = per-batch transpose of xb: [1568,2048] -> [2048,1568]
    transpose_bf16_k<<<dim3(32, 25, 4), 256, 0, stream>>>(
        xb, xbT, N_NODES, CDIM, (long)N_NODES * CDIM, (long)N_NODES * CDIM);

    // ---- h = x @ w_fc1^T  (NT: M=6272,N=2048,K=2048) ----
    gemm_nt<bf16><<<dim3(49, 16, 1), 256, 0, stream>>>(
        xb, wb0, hb, 6272, 2048, 2048, 0, 0, 0);

    // ---- s = h h^T per batch (symmetric: 91 upper-tri tiles, mirrored) ----
    gemm_nt_sym<<<dim3(91, 1, 4), 256, 0, stream>>>(
        hb, sbuf, N_NODES, 2048,
        (long)N_NODES * 2048, (long)N_NODES * N_NODES);

    // ---- lap = 0.5*s^2/colsum + 0.5*I ----
    colsum_part_k<<<dim3(7, 8, 4), 256, 0, stream>>>(sbuf, part);
    colsum_comb_k<<<dim3(7, 4), 256, 0, stream>>>(part, invc);
    lap_build_k<<<dim3(7, N_NODES, 4), 256, 0, stream>>>(sbuf, invc, lap);

    // ---- 3x (lap matmul -> linear -> LN+leaky) ----
    const bf16* wlayer[3] = {wb1, wb2, wb3};
    const float* gl[3] = {g1, g2, g3};
    const float* bl[3] = {b1, b2, b3};
    for (int i = 0; i < 3; i++) {
        const bf16* prevT = (i == 0) ? xbT : zT;
        // outN = lap @ prev = NT(lap, prevT): M=1568, N=2048, K=1568, batched
        gemm_nt<bf16><<<dim3(13, 16, 4), 256, 0, stream>>>(
            lap, prevT, outN, N_NODES, CDIM, N_NODES,
            (long)N_NODES * N_NODES, (long)CDIM * N_NODES, (long)N_NODES * CDIM);
        // y = outN @ w^T  (M=6272, N=2048, K=2048)
        gemm_nt<float><<<dim3(49, 16, 1), 256, 0, stream>>>(
            outN, wlayer[i], ybuf, 6272, 2048, 2048, 0, 0, 0);
        // z = leaky(LN(y))
        ln_leaky_k<<<dim3(6272), 256, 0, stream>>>(ybuf, gl[i], bl[i], zb);
        if (i < 2) {
            transpose_bf16_k<<<dim3(32, 25, 4), 256, 0, stream>>>(
                zb, zT, N_NODES, CDIM, (long)N_NODES * CDIM, (long)N_NODES * CDIM);
        }
    }

    // ---- head ----
    conv1_k<<<dim3(8, 196, 4), 256, 0, stream>>>(zb, conv1_w, conv1_b, tbuf);
    upsample_k<<<dim3(28, 28, 4), 256, 0, stream>>>(tbuf, ubuf);
    // deconv as single GEMM: rbuf[g*1024+oc][b*784+pix] = Wt[9216,2048] x u[3136,2048]^T
    gemm_nt<bf16><<<dim3(72, 25, 1), 256, 0, stream>>>(
        Wt, ubuf, rbuf, 9216, 3136, 2048, 0, 0, 0);
    deconv_scatter_k<<<dim3(4096), 256, 0, stream>>>(rbuf, deconv_b, out);

    (void)in_sizes; (void)n_in; (void)out_size; (void)ws_size;
}

// Round 2
// 1176.549 us; speedup vs baseline: 1.0672x; 1.0672x over previous
//
#include <hip/hip_runtime.h>

typedef __bf16 bf16;
typedef __bf16 bf16x4 __attribute__((ext_vector_type(4)));
typedef __bf16 bf16x8 __attribute__((ext_vector_type(8)));
typedef float f32x4 __attribute__((ext_vector_type(4)));

#define N_NODES 1568
#define CDIM 2048

// ---------------- async global->LDS 16B ----------------
__device__ __forceinline__ void async_copy16(const bf16* g, bf16* l) {
    __builtin_amdgcn_global_load_lds(
        (const __attribute__((address_space(1))) unsigned int*)g,
        (__attribute__((address_space(3))) unsigned int*)l, 16, 0, 0);
}

// =====================================================================
// 256x256 8-wave deep-pipelined NT GEMM (T2 swizzle + T4 counted vmcnt + T5)
// C[M,N] = A[M,K] * B[N,K]^T. K % 64 == 0. 512 threads, 128 KiB LDS, 1 blk/CU.
// LDS layout: [buf][A|B][256 rows][64 k], rows stored with chunk^(row&7)
// XOR swizzle (16B chunks). global_load_lds writes LINEAR dest; the global
// SOURCE address is inverse-swizzled (rule #21: both-sides-or-neither).
// Pipeline: 2 K-tile buffers; tile t+2 staged at iter t after a reads-done
// barrier; vmcnt(8) (counted, never 0 mid-loop) + barrier at iter end waits
// only tile t+1, leaving t+2's 8 loads in flight across the next iteration.
// =====================================================================
template <typename OUT_T>
__global__ __launch_bounds__(512, 2) void gemm256_nt(const bf16* __restrict__ A,
                                                     const bf16* __restrict__ B,
                                                     OUT_T* __restrict__ C,
                                                     int M, int N, int K) {
    __shared__ __align__(16) bf16 lds[2][2][256 * 64];
    const int m0 = blockIdx.x * 256, n0 = blockIdx.y * 256;
    const int t = threadIdx.x;
    const int lane = t & 63, wave = t >> 6;
    const int wm = wave >> 2, wn = wave & 3;      // 2 x 4 wave grid
    const int l15 = lane & 15, quad = lane >> 4, rx7 = l15 & 7;

    // ---- staging addresses: thread t stages 4 chunks of A + 4 of B ----
    // LDS dest linear: (t + i*512)*16B  => row = t/8 + i*64, stored chunk = t&7
    // global logical chunk = stored ^ (row&7) = (t&7) ^ ((t>>3)&7)
    const int cg = (((t & 7) ^ ((t >> 3) & 7)) << 3);   // element offset in row
    const int rb = t >> 3;
    const bf16* ga[4];
    const bf16* gb[4];
#pragma unroll
    for (int i = 0; i < 4; i++) {
        int ra = m0 + rb + i * 64; if (ra >= M) ra = M - 1;
        int rn = n0 + rb + i * 64; if (rn >= N) rn = N - 1;
        ga[i] = A + (long)ra * K + cg;
        gb[i] = B + (long)rn * K + cg;
    }
    const int ldst = t * 8;   // element offset of this thread's first chunk

    f32x4 acc[8][4];
#pragma unroll
    for (int i = 0; i < 8; i++)
#pragma unroll
        for (int j = 0; j < 4; j++) acc[i][j] = (f32x4){0.f, 0.f, 0.f, 0.f};

    auto stage = [&](int buf, int k0) {
        bf16* sAx = &lds[buf][0][0];
        bf16* sBx = &lds[buf][1][0];
#pragma unroll
        for (int i = 0; i < 4; i++)
            async_copy16(ga[i] + k0, sAx + ldst + i * 4096);
#pragma unroll
        for (int i = 0; i < 4; i++)
            async_copy16(gb[i] + k0, sBx + ldst + i * 4096);
    };

    const int NT = K >> 6;
    // prologue: tiles 0 and 1 in flight; wait tile 0 (vmcnt(8) = counted)
    stage(0, 0);
    stage(1, 64);
    asm volatile("s_waitcnt vmcnt(8)" ::: "memory");
    __builtin_amdgcn_s_barrier();

    bf16x8 bfr[4][2], afr[2][2];
    for (int tt = 0; tt < NT; ++tt) {
        const bf16* sA = &lds[tt & 1][0][0];
        const bf16* sB = &lds[tt & 1][1][0];

        auto rdB = [&]() {
#pragma unroll
            for (int nf = 0; nf < 4; ++nf)
#pragma unroll
                for (int kk = 0; kk < 2; ++kk)
                    bfr[nf][kk] = *(const bf16x8*)(sB + (wn * 64 + nf * 16 + l15) * 64 +
                                                   ((((kk << 2) | quad) ^ rx7) << 3));
        };
        auto rdA = [&](int q) {
#pragma unroll
            for (int mi = 0; mi < 2; ++mi)
#pragma unroll
                for (int kk = 0; kk < 2; ++kk)
                    afr[mi][kk] = *(const bf16x8*)(sA + (wm * 128 + (q * 2 + mi) * 16 + l15) * 64 +
                                                   ((((kk << 2) | quad) ^ rx7) << 3));
        };
        auto mfq = [&](int q) {
            __builtin_amdgcn_s_setprio(1);
#pragma unroll
            for (int kk = 0; kk < 2; ++kk)
#pragma unroll
                for (int mi = 0; mi < 2; ++mi)
#pragma unroll
                    for (int nf = 0; nf < 4; ++nf)
                        acc[q * 2 + mi][nf] = __builtin_amdgcn_mfma_f32_16x16x32_bf16(
                            afr[mi][kk], bfr[nf][kk], acc[q * 2 + mi][nf], 0, 0, 0);
            __builtin_amdgcn_s_setprio(0);
        };

        rdB();
        rdA(0); mfq(0);
        rdA(1); mfq(1);
        rdA(2); mfq(2);
        rdA(3);
        // all my reads of buf[tt&1] complete before the barrier -> after it,
        // every wave is done reading; safe to overwrite with tile tt+2.
        asm volatile("s_waitcnt lgkmcnt(0)" ::: "memory");
        __builtin_amdgcn_s_barrier();
        if (tt + 2 < NT) stage(tt & 1, (tt + 2) << 6);
        mfq(3);
        // wait ONLY tile tt+1 (8 loads of tt+2 stay in flight) -> no drain
        if (tt + 2 < NT) { asm volatile("s_waitcnt vmcnt(8)" ::: "memory"); }
        else             { asm volatile("s_waitcnt vmcnt(0)" ::: "memory"); }
        __builtin_amdgcn_s_barrier();
    }

    // epilogue: D[row=quad*4+r][col=l15] per 16x16 frag (m89-verified layout)
#pragma unroll
    for (int mf = 0; mf < 8; ++mf) {
        const int row0 = m0 + wm * 128 + mf * 16 + quad * 4;
#pragma unroll
        for (int nf = 0; nf < 4; ++nf) {
            const int col = n0 + wn * 64 + nf * 16 + l15;
            if (col < N) {
#pragma unroll
                for (int r = 0; r < 4; ++r) {
                    const int row = row0 + r;
                    if (row < M) C[(long)row * N + col] = (OUT_T)acc[mf][nf][r];
                }
            }
        }
    }
}

// ---------------- generic NT bf16 MFMA GEMM (m97-structure, kept for lap) ----------------
template <typename OUT_T>
__global__ __launch_bounds__(256, 2) void gemm_nt(const bf16* __restrict__ A,
                                                  const bf16* __restrict__ B,
                                                  OUT_T* __restrict__ C,
                                                  int M, int N, int K,
                                                  long sAb, long sBb, long sCb) {
    __shared__ __align__(16) bf16 sA[128 * 32];
    __shared__ __align__(16) bf16 sB[128 * 32];
    const int bz = blockIdx.z;
    A += (long)bz * sAb; B += (long)bz * sBb; C += (long)bz * sCb;
    const int m0 = blockIdx.x * 128, n0 = blockIdx.y * 128;
    const int t = threadIdx.x;
    const int lane = t & 63, wave = t >> 6;
    const int wr = wave >> 1, wc = wave & 1;
    const int l15 = lane & 15, quad = lane >> 4;

    f32x4 acc[4][4];
#pragma unroll
    for (int i = 0; i < 4; i++)
#pragma unroll
        for (int j = 0; j < 4; j++) acc[i][j] = (f32x4){0.f, 0.f, 0.f, 0.f};

    const int ko = (t & 3) * 8;
    int ra1 = m0 + (t >> 2);          if (ra1 >= M) ra1 = M - 1;
    int ra2 = m0 + ((t + 256) >> 2);  if (ra2 >= M) ra2 = M - 1;
    int rb1 = n0 + (t >> 2);          if (rb1 >= N) rb1 = N - 1;
    int rb2 = n0 + ((t + 256) >> 2);  if (rb2 >= N) rb2 = N - 1;
    const bf16* gA1 = A + (long)ra1 * K + ko;
    const bf16* gA2 = A + (long)ra2 * K + ko;
    const bf16* gB1 = B + (long)rb1 * K + ko;
    const bf16* gB2 = B + (long)rb2 * K + ko;
    bf16* lA1 = sA + t * 8;  bf16* lA2 = sA + (t + 256) * 8;
    bf16* lB1 = sB + t * 8;  bf16* lB2 = sB + (t + 256) * 8;

    for (int k0 = 0; k0 < K; k0 += 32) {
        __syncthreads();
        async_copy16(gA1 + k0, lA1);
        async_copy16(gA2 + k0, lA2);
        async_copy16(gB1 + k0, lB1);
        async_copy16(gB2 + k0, lB2);
        __syncthreads();
        bf16x8 af[4], bfr[4];
#pragma unroll
        for (int i = 0; i < 4; i++)
            af[i] = *(const bf16x8*)(sA + (wr * 64 + i * 16 + l15) * 32 + quad * 8);
#pragma unroll
        for (int j = 0; j < 4; j++)
            bfr[j] = *(const bf16x8*)(sB + (wc * 64 + j * 16 + l15) * 32 + quad * 8);
#pragma unroll
        for (int i = 0; i < 4; i++)
#pragma unroll
            for (int j = 0; j < 4; j++)
                acc[i][j] = __builtin_amdgcn_mfma_f32_16x16x32_bf16(af[i], bfr[j], acc[i][j], 0, 0, 0);
    }
#pragma unroll
    for (int i = 0; i < 4; i++) {
        const int row0 = m0 + wr * 64 + i * 16 + quad * 4;
#pragma unroll
        for (int j = 0; j < 4; j++) {
            const int col = n0 + wc * 64 + j * 16 + l15;
            if (col < N) {
#pragma unroll
                for (int r = 0; r < 4; r++) {
                    const int row = row0 + r;
                    if (row < M) C[(long)row * N + col] = (OUT_T)acc[i][j][r];
                }
            }
        }
    }
}

// ---------------- symmetric NT GEMM: C = A A^T (f32 out) ----------------
__global__ __launch_bounds__(256, 2) void gemm_nt_sym(const bf16* __restrict__ A,
                                                      float* __restrict__ C,
                                                      int M, int K,
                                                      long sAb, long sCb) {
    __shared__ __align__(16) bf16 sA[128 * 32];
    __shared__ __align__(16) bf16 sB[128 * 32];
    const int bz = blockIdx.z;
    A += (long)bz * sAb; C += (long)bz * sCb;
    int rem = blockIdx.x, bi = 0;
    while (rem >= 13 - bi) { rem -= 13 - bi; bi++; }
    const int bj = bi + rem;
    const int m0 = bi * 128, n0 = bj * 128;
    const int t = threadIdx.x;
    const int lane = t & 63, wave = t >> 6;
    const int wr = wave >> 1, wc = wave & 1;
    const int l15 = lane & 15, quad = lane >> 4;

    f32x4 acc[4][4];
#pragma unroll
    for (int i = 0; i < 4; i++)
#pragma unroll
        for (int j = 0; j < 4; j++) acc[i][j] = (f32x4){0.f, 0.f, 0.f, 0.f};

    const int ko = (t & 3) * 8;
    int ra1 = m0 + (t >> 2);          if (ra1 >= M) ra1 = M - 1;
    int ra2 = m0 + ((t + 256) >> 2);  if (ra2 >= M) ra2 = M - 1;
    int rb1 = n0 + (t >> 2);          if (rb1 >= M) rb1 = M - 1;
    int rb2 = n0 + ((t + 256) >> 2);  if (rb2 >= M) rb2 = M - 1;
    const bf16* gA1 = A + (long)ra1 * K + ko;
    const bf16* gA2 = A + (long)ra2 * K + ko;
    const bf16* gB1 = A + (long)rb1 * K + ko;
    const bf16* gB2 = A + (long)rb2 * K + ko;
    bf16* lA1 = sA + t * 8;  bf16* lA2 = sA + (t + 256) * 8;
    bf16* lB1 = sB + t * 8;  bf16* lB2 = sB + (t + 256) * 8;

    for (int k0 = 0; k0 < K; k0 += 32) {
        __syncthreads();
        async_copy16(gA1 + k0, lA1);
        async_copy16(gA2 + k0, lA2);
        async_copy16(gB1 + k0, lB1);
        async_copy16(gB2 + k0, lB2);
        __syncthreads();
        bf16x8 af[4], bfr[4];
#pragma unroll
        for (int i = 0; i < 4; i++)
            af[i] = *(const bf16x8*)(sA + (wr * 64 + i * 16 + l15) * 32 + quad * 8);
#pragma unroll
        for (int j = 0; j < 4; j++)
            bfr[j] = *(const bf16x8*)(sB + (wc * 64 + j * 16 + l15) * 32 + quad * 8);
#pragma unroll
        for (int i = 0; i < 4; i++)
#pragma unroll
            for (int j = 0; j < 4; j++)
                acc[i][j] = __builtin_amdgcn_mfma_f32_16x16x32_bf16(af[i], bfr[j], acc[i][j], 0, 0, 0);
    }
    const bool mirror = (bi != bj);
#pragma unroll
    for (int i = 0; i < 4; i++) {
        const int row0 = m0 + wr * 64 + i * 16 + quad * 4;
#pragma unroll
        for (int j = 0; j < 4; j++) {
            const int col = n0 + wc * 64 + j * 16 + l15;
            if (col < M) {
#pragma unroll
                for (int r = 0; r < 4; r++) {
                    const int row = row0 + r;
                    if (row < M) {
                        const float v = acc[i][j][r];
                        C[(long)row * M + col] = v;
                        if (mirror) C[(long)col * M + row] = v;
                    }
                }
            }
        }
    }
}

// ---------------- f32 -> bf16 cast (vectorized) ----------------
__global__ __launch_bounds__(256) void cast_f32_bf16_k(const float* __restrict__ in,
                                                       bf16* __restrict__ out, long n) {
    long i = ((long)blockIdx.x * 256 + threadIdx.x) * 4;
    if (i >= n) return;
    float4 v = *(const float4*)(in + i);
    bf16x4 o;
    o[0] = (bf16)v.x; o[1] = (bf16)v.y; o[2] = (bf16)v.z; o[3] = (bf16)v.w;
    *(bf16x4*)(out + i) = o;
}

__global__ __launch_bounds__(256) void cast4_f32_bf16_k(const float* __restrict__ a,
                                                        const float* __restrict__ b,
                                                        const float* __restrict__ c,
                                                        const float* __restrict__ d,
                                                        bf16* __restrict__ out, long n) {
    const int w = blockIdx.y;
    const float* in = (w == 0) ? a : (w == 1) ? b : (w == 2) ? c : d;
    bf16* o = out + (long)w * n;
    long i = ((long)blockIdx.x * 256 + threadIdx.x) * 4;
    if (i >= n) return;
    float4 v = *(const float4*)(in + i);
    bf16x4 ov;
    ov[0] = (bf16)v.x; ov[1] = (bf16)v.y; ov[2] = (bf16)v.z; ov[3] = (bf16)v.w;
    *(bf16x4*)(o + i) = ov;
}

// ---------------- bf16 tiled transpose (batched) ----------------
__global__ __launch_bounds__(256) void transpose_bf16_k(const bf16* __restrict__ in,
                                                        bf16* __restrict__ out,
                                                        int R, int C, long sIn, long sOut) {
    __shared__ bf16 tile[64][65];
    in += (long)blockIdx.z * sIn;
    out += (long)blockIdx.z * sOut;
    const int r0 = blockIdx.y * 64, c0 = blockIdx.x * 64;
    const int tx = threadIdx.x & 63, ty = threadIdx.x >> 6;
#pragma unroll
    for (int i = 0; i < 16; i++) {
        int r = ty * 16 + i;
        int gr = r0 + r, gc = c0 + tx;
        tile[r][tx] = (gr < R && gc < C) ? in[(long)gr * C + gc] : (bf16)0.f;
    }
    __syncthreads();
#pragma unroll
    for (int i = 0; i < 16; i++) {
        int c = ty * 16 + i;
        int gc = c0 + c, gr = r0 + tx;
        if (gc < C && gr < R) out[(long)gc * R + gr] = tile[tx][c];
    }
}

// ---------------- adjacency: column sums of s^2 (partials + combine) ----------------
__global__ __launch_bounds__(256) void colsum_part_k(const float* __restrict__ s,
                                                     float* __restrict__ part) {
    int m = blockIdx.x * 256 + threadIdx.x;
    if (m >= N_NODES) return;
    int y = blockIdx.y, b = blockIdx.z;
    const float* sb = s + (long)b * N_NODES * N_NODES;
    float acc = 0.f;
    for (int n = y * 196; n < y * 196 + 196; ++n) {
        float v = sb[(long)n * N_NODES + m];
        acc += v * v;
    }
    part[((long)y * 4 + b) * N_NODES + m] = acc;
}

__global__ __launch_bounds__(256) void colsum_comb_k(const float* __restrict__ part,
                                                     float* __restrict__ inv) {
    int m = blockIdx.x * 256 + threadIdx.x;
    if (m >= N_NODES) return;
    int b = blockIdx.y;
    float a = 0.f;
#pragma unroll
    for (int y = 0; y < 8; y++) a += part[((long)y * 4 + b) * N_NODES + m];
    inv[(long)b * N_NODES + m] = 1.0f / a;
}

// lap[n,m] = 0.5 * s^2[n,m] * inv[m] + 0.5*(n==m)
__global__ __launch_bounds__(256) void lap_build_k(const float* __restrict__ s,
                                                   const float* __restrict__ inv,
                                                   bf16* __restrict__ lap) {
    int m = blockIdx.x * 256 + threadIdx.x;
    if (m >= N_NODES) return;
    int n = blockIdx.y, b = blockIdx.z;
    long off = (long)b * N_NODES * N_NODES + (long)n * N_NODES + m;
    float v = s[off];
    float l = 0.5f * v * v * inv[(long)b * N_NODES + m];
    if (n == m) l += 0.5f;
    lap[off] = (bf16)l;
}

// ---------------- LayerNorm(2048) + LeakyReLU(0.1), row-per-block ----------------
__global__ __launch_bounds__(256) void ln_leaky_k(const float* __restrict__ y,
                                                  const float* __restrict__ g,
                                                  const float* __restrict__ beta,
                                                  bf16* __restrict__ z) {
    const long row = blockIdx.x;
    const float* yr = y + row * CDIM;
    const int t = threadIdx.x;
    float v[8];
    float s = 0.f, ss = 0.f;
#pragma unroll
    for (int i = 0; i < 8; i++) {
        float x = yr[t + 256 * i];
        v[i] = x; s += x; ss += x * x;
    }
#pragma unroll
    for (int o = 32; o > 0; o >>= 1) {
        s += __shfl_down(s, o);
        ss += __shfl_down(ss, o);
    }
    __shared__ float sh[8];
    const int wave = t >> 6;
    if ((t & 63) == 0) { sh[wave] = s; sh[wave + 4] = ss; }
    __syncthreads();
    if (t == 0) {
        float a = 0.f, b2 = 0.f;
#pragma unroll
        for (int w = 0; w < 4; w++) { a += sh[w]; b2 += sh[w + 4]; }
        sh[0] = a; sh[4] = b2;
    }
    __syncthreads();
    const float mean = sh[0] * (1.f / 2048.f);
    const float var = sh[4] * (1.f / 2048.f) - mean * mean;
    const float invs = rsqrtf(var + 1e-5f);
    bf16* zr = z + row * CDIM;
#pragma unroll
    for (int i = 0; i < 8; i++) {
        int c = t + 256 * i;
        float o = (v[i] - mean) * invs * g[c] + beta[c];
        o = o > 0.f ? o : 0.1f * o;
        zr[c] = (bf16)o;
    }
}

// ---------------- head: conv1 over 8 frame channels ----------------
__global__ __launch_bounds__(256) void conv1_k(const bf16* __restrict__ z,
                                               const float* __restrict__ cw,
                                               const float* __restrict__ cb,
                                               bf16* __restrict__ tb) {
    const int b = blockIdx.z, hw = blockIdx.y;
    const int c = blockIdx.x * 256 + threadIdx.x;
    float acc = cb[0];
#pragma unroll
    for (int f = 0; f < 8; f++)
        acc += (float)z[((long)b * N_NODES + f * 196 + hw) * CDIM + c] * cw[f];
    tb[((long)b * 196 + hw) * CDIM + c] = (bf16)acc;
}

// ---------------- bilinear x2 upsample, half-pixel, edge clamp ----------------
__global__ __launch_bounds__(256) void upsample_k(const bf16* __restrict__ tb,
                                                  bf16* __restrict__ u) {
    const int b = blockIdx.z, i = blockIdx.y, j = blockIdx.x;
    const float si = 0.5f * i - 0.25f, sj = 0.5f * j - 0.25f;
    const int i0 = (int)floorf(si), j0 = (int)floorf(sj);
    const float wi = si - i0, wj = sj - j0;
    const int i0c = max(i0, 0), i1c = min(i0 + 1, 13);
    const int j0c = max(j0, 0), j1c = min(j0 + 1, 13);
    const bf16* base = tb + (long)b * 196 * CDIM;
    const long r00 = ((long)i0c * 14 + j0c) * CDIM, r01 = ((long)i0c * 14 + j1c) * CDIM;
    const long r10 = ((long)i1c * 14 + j0c) * CDIM, r11 = ((long)i1c * 14 + j1c) * CDIM;
    bf16* ur = u + ((long)(b * 28 + i) * 28 + j) * CDIM;
    const float w00 = (1.f - wi) * (1.f - wj), w01 = (1.f - wi) * wj;
    const float w10 = wi * (1.f - wj), w11 = wi * wj;
    for (int k = 0; k < 8; k++) {
        int cc = threadIdx.x + 256 * k;
        float v = w00 * (float)base[r00 + cc] + w01 * (float)base[r01 + cc] +
                  w10 * (float)base[r10 + cc] + w11 * (float)base[r11 + cc];
        ur[cc] = (bf16)v;
    }
}

// ---------------- deconv weight transform ----------------
__global__ __launch_bounds__(256) void wt_k(const float* __restrict__ dw,
                                            bf16* __restrict__ Wt) {
    const int ic = blockIdx.x * 256 + threadIdx.x;
    const int oc = blockIdx.y;
    const float* src = dw + ((long)ic * 1024 + oc) * 9;
#pragma unroll
    for (int r = 0; r < 3; r++)
#pragma unroll
        for (int s = 0; s < 3; s++) {
            int kh = 2 - r, kw = 2 - s;
            Wt[((long)(kh * 3 + kw) * 1024 + oc) * 2048 + ic] = (bf16)src[r * 3 + s];
        }
}

// ---------------- deconv scatter ----------------
__global__ __launch_bounds__(256) void deconv_scatter_k(const bf16* __restrict__ r,
                                                        const float* __restrict__ db,
                                                        float* __restrict__ out) {
    const int blk = blockIdx.x;          // 4096 = b*1024 + oc
    const int b = blk >> 10, oc = blk & 1023;
    const float bias = db[oc];
    float* ob = out + (long)blk * 82 * 82;
    for (int e = threadIdx.x; e < 82 * 82; e += 256) {
        const int oh = e / 82, ow = e - oh * 82;
        const int mh = oh % 3, mw = ow % 3;
        const int kh = (mh == 0) ? 1 : ((mh == 1) ? 0 : 2);
        const int kw = (mw == 0) ? 1 : ((mw == 1) ? 0 : 2);
        const int ih = (oh - (1 - kh)) / 3;
        const int iw = (ow - (1 - kw)) / 3;
        const int g = kh * 3 + kw;
        ob[e] = (float)r[(long)(g * 1024 + oc) * 3136 + b * 784 + ih * 28 + iw] + bias;
    }
}

// =====================================================================
extern "C" void kernel_launch(void* const* d_in, const int* in_sizes, int n_in,
                              void* d_out, int out_size, void* d_ws, size_t ws_size,
                              hipStream_t stream) {
    const float* x        = (const float*)d_in[0];
    const float* w_fc1    = (const float*)d_in[1];
    const float* w1       = (const float*)d_in[2];
    const float* g1       = (const float*)d_in[3];
    const float* b1       = (const float*)d_in[4];
    const float* w2       = (const float*)d_in[5];
    const float* g2       = (const float*)d_in[6];
    const float* b2       = (const float*)d_in[7];
    const float* w3       = (const float*)d_in[8];
    const float* g3       = (const float*)d_in[9];
    const float* b3       = (const float*)d_in[10];
    const float* conv1_w  = (const float*)d_in[11];
    const float* conv1_b  = (const float*)d_in[12];
    const float* deconv_w = (const float*)d_in[13];
    const float* deconv_b = (const float*)d_in[14];
    float* out = (float*)d_out;

    // ---- workspace layout (bytes) ----
    char* W = (char*)d_ws;
    bf16* wb   = (bf16*)(W + 0);            // 4 x 2048x2048 bf16 = 33,554,432
    bf16* xb   = (bf16*)(W + 33554432);     // 6272x2048 bf16 (later: z)
    bf16* xbT  = (bf16*)(W + 59244544);     // 4 x 2048x1568 bf16 (later: zT)
    bf16* hb   = (bf16*)(W + 84934656);     // 6272x2048 bf16 (later: outN)
    bf16* lap  = (bf16*)(W + 110624768);    // 4 x 1568x1568 bf16 = 19,668,992
    bf16* tbuf = (bf16*)(W + 130293760);    // 4 x 196x2048 bf16 = 3,211,264
    bf16* ubuf = (bf16*)(W + 133505024);    // 4 x 784x2048 bf16 = 12,845,056
    bf16* Wt   = (bf16*)(W + 146350080);    // 9 x 1024x2048 bf16 = 37,748,736
    float* ybuf = (float*)(W + 184098816);  // 6272x2048 f32 = 51,380,224
    float* sbuf = (float*)(W + 184098816);  // s overlays y (dead before first y write)
    float* part = (float*)(W + 235479040);  // 8x4x1568 f32
    float* invc = (float*)(W + 235679744);  // 4x1568 f32
    bf16* rbuf = (bf16*)(W + 0);            // 9216 x 3136 bf16 (overlays wb/xb, dead then)
    bf16* zb = xb;
    bf16* zT = xbT;
    bf16* outN = hb;

    const long WMAT = (long)2048 * 2048;
    bf16* wb0 = wb, *wb1 = wb + WMAT, *wb2 = wb + 2 * WMAT, *wb3 = wb + 3 * WMAT;

    // ---- weight / input casts ----
    cast4_f32_bf16_k<<<dim3(4096, 4), 256, 0, stream>>>(w_fc1, w1, w2, w3, wb, WMAT);
    cast_f32_bf16_k<<<dim3(12544), 256, 0, stream>>>(x, xb, (long)6272 * 2048);
    wt_k<<<dim3(8, 1024), 256, 0, stream>>>(deconv_w, Wt);

    transpose_bf16_k<<<dim3(32, 25, 4), 256, 0, stream>>>(
        xb, xbT, N_NODES, CDIM, (long)N_NODES * CDIM, (long)N_NODES * CDIM);

    // ---- h = x @ w_fc1^T  (M=6272,N=2048,K=2048) : 256^2 pipelined ----
    gemm256_nt<bf16><<<dim3(25, 8), 512, 0, stream>>>(xb, wb0, hb, 6272, 2048, 2048);

    // ---- s = h h^T per batch ----
    gemm_nt_sym<<<dim3(91, 1, 4), 256, 0, stream>>>(
        hb, sbuf, N_NODES, 2048,
        (long)N_NODES * 2048, (long)N_NODES * N_NODES);

    // ---- lap ----
    colsum_part_k<<<dim3(7, 8, 4), 256, 0, stream>>>(sbuf, part);
    colsum_comb_k<<<dim3(7, 4), 256, 0, stream>>>(part, invc);
    lap_build_k<<<dim3(7, N_NODES, 4), 256, 0, stream>>>(sbuf, invc, lap);

    // ---- 3x (lap matmul -> linear -> LN+leaky) ----
    const bf16* wlayer[3] = {wb1, wb2, wb3};
    const float* gl[3] = {g1, g2, g3};
    const float* bl[3] = {b1, b2, b3};
    for (int i = 0; i < 3; i++) {
        const bf16* prevT = (i == 0) ? xbT : zT;
        // outN = lap @ prev (K=1568: stays on m97-structure kernel)
        gemm_nt<bf16><<<dim3(13, 16, 4), 256, 0, stream>>>(
            lap, prevT, outN, N_NODES, CDIM, N_NODES,
            (long)N_NODES * N_NODES, (long)CDIM * N_NODES, (long)N_NODES * CDIM);
        // y = outN @ w^T : 256^2 pipelined, f32 out
        gemm256_nt<float><<<dim3(25, 8), 512, 0, stream>>>(
            outN, wlayer[i], ybuf, 6272, 2048, 2048);
        ln_leaky_k<<<dim3(6272), 256, 0, stream>>>(ybuf, gl[i], bl[i], zb);
        if (i < 2) {
            transpose_bf16_k<<<dim3(32, 25, 4), 256, 0, stream>>>(
                zb, zT, N_NODES, CDIM, (long)N_NODES * CDIM, (long)N_NODES * CDIM);
        }
    }

    // ---- head ----
    conv1_k<<<dim3(8, 196, 4), 256, 0, stream>>>(zb, conv1_w, conv1_b, tbuf);
    upsample_k<<<dim3(28, 28, 4), 256, 0, stream>>>(tbuf, ubuf);
    // deconv GEMM: 256^2 pipelined (M=9216, N=3136, K=2048)
    gemm256_nt<bf16><<<dim3(36, 13), 512, 0, stream>>>(Wt, ubuf, rbuf, 9216, 3136, 2048);
    deconv_scatter_k<<<dim3(4096), 256, 0, stream>>>(rbuf, deconv_b, out);

    (void)in_sizes; (void)n_in; (void)out_size; (void)ws_size;
}

// Round 3
// 1043.313 us; speedup vs baseline: 1.2034x; 1.1277x over previous
//
#include <hip/hip_runtime.h>

typedef __bf16 bf16;
typedef __bf16 bf16x4 __attribute__((ext_vector_type(4)));
typedef __bf16 bf16x8 __attribute__((ext_vector_type(8)));
typedef float f32x4 __attribute__((ext_vector_type(4)));

#define N_NODES 1568
#define CDIM 2048
#define LAP_K 1664   // 1568 padded to 26*64 so the 8-phase GEMM (NT even) applies

// ---------------- async global->LDS 16B ----------------
__device__ __forceinline__ void async_copy16(const bf16* g, bf16* l) {
    __builtin_amdgcn_global_load_lds(
        (const __attribute__((address_space(1))) unsigned int*)g,
        (__attribute__((address_space(3))) unsigned int*)l, 16, 0, 0);
}

// =====================================================================
// 256x256 8-wave 8-phase NT GEMM (m201 template port: T2+T3+T4+T5)
// C[M,N] = A[M,K]*B[N,K]^T, K%128==0 (NT=K/64 even). 512 thr, 128KiB LDS.
// Per phase: {ds_read subtile | stage 1 half-tile(2 gload_lds) | barrier |
//             lgkmcnt(0)+sched_barrier | setprio(1) 16 MFMA setprio(0) |
//             [vmcnt(4) at ph4/8] | barrier}.  8 phases / 2 K-tiles.
// Region-free proof: B of buf fully read in its phase 1 (8 reads held in
// regs) -> stageable from phase 2 of that tile onward; A-halves fully read
// by end of phase 4. Schedule stages: p1,p2: A(t+1)->otherbuf (freed at
// prev p8 barrier); p3,p4: B(t+2)->curbuf-B (freed after p1); p5,p6:
// A(t+2)->curbuf-A (freed after p4); p7,p8: B(t+3)->otherbuf-B (freed
// after p5). vmcnt(4): FIFO outstanding <=12, oldest 8 (= next tile's
// operands) retired, newest 4 stay in flight -> never a full drain.
// Tail: stage k0 clamped to tile 0 (in-bounds garbage, never read) so the
// vmcnt immediates remain exact.
// LDS swizzle (verified R2, conflicts==0): row r, 16B-chunk c stored at
// c^(r&7); gload_lds dest linear, SOURCE pre-inverse-swizzled (rule #21).
// =====================================================================
template <typename OUT_T>
__global__ __launch_bounds__(512, 2) void gemm256_nt(const bf16* __restrict__ A,
                                                     const bf16* __restrict__ B,
                                                     OUT_T* __restrict__ C,
                                                     int M, int N, int K,
                                                     long sAb, long sBb, long sCb) {
    __shared__ __align__(16) bf16 lds[2][2][256 * 64];
    const int bz = blockIdx.z;
    A += (long)bz * sAb; B += (long)bz * sBb; C += (long)bz * sCb;
    const int m0 = blockIdx.x * 256, n0 = blockIdx.y * 256;
    const int t = threadIdx.x;
    const int lane = t & 63, wave = t >> 6;
    const int wm = wave >> 2, wn = wave & 3;      // 2 x 4 wave grid
    const int l15 = lane & 15, quad = lane >> 4, rx7 = l15 & 7;

    const int cg = (((t & 7) ^ ((t >> 3) & 7)) << 3);   // inverse-swizzled k-chunk
    const int rb = t >> 3;
    const bf16* ga[4];
    const bf16* gb[4];
#pragma unroll
    for (int i = 0; i < 4; i++) {
        int ra = m0 + rb + i * 64; if (ra >= M) ra = M - 1;
        int rn = n0 + rb + i * 64; if (rn >= N) rn = N - 1;
        ga[i] = A + (long)ra * K + cg;
        gb[i] = B + (long)rn * K + cg;
    }
    const int ldst = t * 8;
    const int NT = K >> 6, NI = NT >> 1;

    auto stageA = [&](int buf, int h, int tt) {       // h: 0/1 -> rows h*128..+127
        const int k0 = (tt < NT) ? (tt << 6) : 0;     // clamp: tail garbage unread
        bf16* s = &lds[buf][0][0] + ldst;
        async_copy16(ga[2 * h] + k0,     s + (2 * h) * 4096);
        async_copy16(ga[2 * h + 1] + k0, s + (2 * h + 1) * 4096);
    };
    auto stageB = [&](int buf, int h, int tt) {
        const int k0 = (tt < NT) ? (tt << 6) : 0;
        bf16* s = &lds[buf][1][0] + ldst;
        async_copy16(gb[2 * h] + k0,     s + (2 * h) * 4096);
        async_copy16(gb[2 * h + 1] + k0, s + (2 * h + 1) * 4096);
    };

    // prologue stages: A(0),B(0) full + B(1) full = 12 ops
    stageA(0, 0, 0); stageA(0, 1, 0);
    stageB(0, 0, 0); stageB(0, 1, 0);
    stageB(1, 0, 1); stageB(1, 1, 1);

    f32x4 acc[8][4];
#pragma unroll
    for (int i = 0; i < 8; i++)
#pragma unroll
        for (int j = 0; j < 4; j++) acc[i][j] = (f32x4){0.f, 0.f, 0.f, 0.f};

    asm volatile("s_waitcnt vmcnt(4)" ::: "memory");   // tile0 landed, B(1) flying
    __builtin_amdgcn_s_barrier();

    bf16x8 bfr[4][2], afr[2][2];
    auto rdB = [&](int cb) {
        const bf16* sB = &lds[cb][1][0];
#pragma unroll
        for (int nf = 0; nf < 4; ++nf)
#pragma unroll
            for (int kk = 0; kk < 2; ++kk)
                bfr[nf][kk] = *(const bf16x8*)(sB + (wn * 64 + nf * 16 + l15) * 64 +
                                               ((((kk << 2) | quad) ^ rx7) << 3));
    };
    auto rdA = [&](int cb, int q) {
        const bf16* sA = &lds[cb][0][0];
#pragma unroll
        for (int mi = 0; mi < 2; ++mi)
#pragma unroll
            for (int kk = 0; kk < 2; ++kk)
                afr[mi][kk] = *(const bf16x8*)(sA + (wm * 128 + (q * 2 + mi) * 16 + l15) * 64 +
                                               ((((kk << 2) | quad) ^ rx7) << 3));
    };
    auto sync_mfma = [&](int q, bool vm) {
        __builtin_amdgcn_s_barrier();
        asm volatile("s_waitcnt lgkmcnt(0)" ::: "memory");
        __builtin_amdgcn_sched_barrier(0);               // rule #18: pin MFMA after wait
        __builtin_amdgcn_s_setprio(1);
#pragma unroll
        for (int kk = 0; kk < 2; ++kk)
#pragma unroll
            for (int mi = 0; mi < 2; ++mi)
#pragma unroll
                for (int nf = 0; nf < 4; ++nf)
                    acc[q * 2 + mi][nf] = __builtin_amdgcn_mfma_f32_16x16x32_bf16(
                        afr[mi][kk], bfr[nf][kk], acc[q * 2 + mi][nf], 0, 0, 0);
        __builtin_amdgcn_s_setprio(0);
        if (vm) asm volatile("s_waitcnt vmcnt(4)" ::: "memory");
        __builtin_amdgcn_s_barrier();
    };

    for (int j = 0; j < NI; ++j) {
        const int t0 = 2 * j;
        rdB(0); rdA(0, 0); stageA(1, 0, t0 + 1); sync_mfma(0, false);
        rdA(0, 1);         stageA(1, 1, t0 + 1); sync_mfma(1, false);
        rdA(0, 2);         stageB(0, 0, t0 + 2); sync_mfma(2, false);
        rdA(0, 3);         stageB(0, 1, t0 + 2); sync_mfma(3, true);
        rdB(1); rdA(1, 0); stageA(0, 0, t0 + 2); sync_mfma(0, false);
        rdA(1, 1);         stageA(0, 1, t0 + 2); sync_mfma(1, false);
        rdA(1, 2);         stageB(1, 0, t0 + 3); sync_mfma(2, false);
        rdA(1, 3);         stageB(1, 1, t0 + 3); sync_mfma(3, true);
    }
    asm volatile("s_waitcnt vmcnt(0)" ::: "memory");   // drain DMAs before endpgm

    // epilogue: D[row=quad*4+r][col=l15] per 16x16 frag (m89-verified layout)
#pragma unroll
    for (int mf = 0; mf < 8; ++mf) {
        const int row0 = m0 + wm * 128 + mf * 16 + quad * 4;
#pragma unroll
        for (int nf = 0; nf < 4; ++nf) {
            const int col = n0 + wn * 64 + nf * 16 + l15;
            if (col < N) {
#pragma unroll
                for (int r = 0; r < 4; ++r) {
                    const int row = row0 + r;
                    if (row < M) C[(long)row * N + col] = (OUT_T)acc[mf][nf][r];
                }
            }
        }
    }
}

// ---------------- symmetric variant: C = A A^T (f32), upper-tri tiles ----------------
__global__ __launch_bounds__(512, 2) void gemm256_sym(const bf16* __restrict__ A,
                                                      float* __restrict__ C,
                                                      int M, int K,
                                                      long sAb, long sCb) {
    __shared__ __align__(16) bf16 lds[2][2][256 * 64];
    const int bz = blockIdx.z;
    A += (long)bz * sAb; C += (long)bz * sCb;
    const int side = (M + 255) >> 8;
    int rem = blockIdx.x, bi = 0;
    while (rem >= side - bi) { rem -= side - bi; bi++; }
    const int bj = bi + rem;
    const int m0 = bi * 256, n0 = bj * 256;
    const int t = threadIdx.x;
    const int lane = t & 63, wave = t >> 6;
    const int wm = wave >> 2, wn = wave & 3;
    const int l15 = lane & 15, quad = lane >> 4, rx7 = l15 & 7;

    const int cg = (((t & 7) ^ ((t >> 3) & 7)) << 3);
    const int rb = t >> 3;
    const bf16* ga[4];
    const bf16* gb[4];
#pragma unroll
    for (int i = 0; i < 4; i++) {
        int ra = m0 + rb + i * 64; if (ra >= M) ra = M - 1;
        int rn = n0 + rb + i * 64; if (rn >= M) rn = M - 1;
        ga[i] = A + (long)ra * K + cg;
        gb[i] = A + (long)rn * K + cg;
    }
    const int ldst = t * 8;
    const int NT = K >> 6, NI = NT >> 1;

    auto stageA = [&](int buf, int h, int tt) {
        const int k0 = (tt < NT) ? (tt << 6) : 0;
        bf16* s = &lds[buf][0][0] + ldst;
        async_copy16(ga[2 * h] + k0,     s + (2 * h) * 4096);
        async_copy16(ga[2 * h + 1] + k0, s + (2 * h + 1) * 4096);
    };
    auto stageB = [&](int buf, int h, int tt) {
        const int k0 = (tt < NT) ? (tt << 6) : 0;
        bf16* s = &lds[buf][1][0] + ldst;
        async_copy16(gb[2 * h] + k0,     s + (2 * h) * 4096);
        async_copy16(gb[2 * h + 1] + k0, s + (2 * h + 1) * 4096);
    };

    stageA(0, 0, 0); stageA(0, 1, 0);
    stageB(0, 0, 0); stageB(0, 1, 0);
    stageB(1, 0, 1); stageB(1, 1, 1);

    f32x4 acc[8][4];
#pragma unroll
    for (int i = 0; i < 8; i++)
#pragma unroll
        for (int j = 0; j < 4; j++) acc[i][j] = (f32x4){0.f, 0.f, 0.f, 0.f};

    asm volatile("s_waitcnt vmcnt(4)" ::: "memory");
    __builtin_amdgcn_s_barrier();

    bf16x8 bfr[4][2], afr[2][2];
    auto rdB = [&](int cb) {
        const bf16* sB = &lds[cb][1][0];
#pragma unroll
        for (int nf = 0; nf < 4; ++nf)
#pragma unroll
            for (int kk = 0; kk < 2; ++kk)
                bfr[nf][kk] = *(const bf16x8*)(sB + (wn * 64 + nf * 16 + l15) * 64 +
                                               ((((kk << 2) | quad) ^ rx7) << 3));
    };
    auto rdA = [&](int cb, int q) {
        const bf16* sA = &lds[cb][0][0];
#pragma unroll
        for (int mi = 0; mi < 2; ++mi)
#pragma unroll
            for (int kk = 0; kk < 2; ++kk)
                afr[mi][kk] = *(const bf16x8*)(sA + (wm * 128 + (q * 2 + mi) * 16 + l15) * 64 +
                                               ((((kk << 2) | quad) ^ rx7) << 3));
    };
    auto sync_mfma = [&](int q, bool vm) {
        __builtin_amdgcn_s_barrier();
        asm volatile("s_waitcnt lgkmcnt(0)" ::: "memory");
        __builtin_amdgcn_sched_barrier(0);
        __builtin_amdgcn_s_setprio(1);
#pragma unroll
        for (int kk = 0; kk < 2; ++kk)
#pragma unroll
            for (int mi = 0; mi < 2; ++mi)
#pragma unroll
                for (int nf = 0; nf < 4; ++nf)
                    acc[q * 2 + mi][nf] = __builtin_amdgcn_mfma_f32_16x16x32_bf16(
                        afr[mi][kk], bfr[nf][kk], acc[q * 2 + mi][nf], 0, 0, 0);
        __builtin_amdgcn_s_setprio(0);
        if (vm) asm volatile("s_waitcnt vmcnt(4)" ::: "memory");
        __builtin_amdgcn_s_barrier();
    };

    for (int j = 0; j < NI; ++j) {
        const int t0 = 2 * j;
        rdB(0); rdA(0, 0); stageA(1, 0, t0 + 1); sync_mfma(0, false);
        rdA(0, 1);         stageA(1, 1, t0 + 1); sync_mfma(1, false);
        rdA(0, 2);         stageB(0, 0, t0 + 2); sync_mfma(2, false);
        rdA(0, 3);         stageB(0, 1, t0 + 2); sync_mfma(3, true);
        rdB(1); rdA(1, 0); stageA(0, 0, t0 + 2); sync_mfma(0, false);
        rdA(1, 1);         stageA(0, 1, t0 + 1 + 1); sync_mfma(1, false);
        rdA(1, 2);         stageB(1, 0, t0 + 3); sync_mfma(2, false);
        rdA(1, 3);         stageB(1, 1, t0 + 3); sync_mfma(3, true);
    }
    asm volatile("s_waitcnt vmcnt(0)" ::: "memory");

    const bool mirror = (bi != bj);
#pragma unroll
    for (int mf = 0; mf < 8; ++mf) {
        const int row0 = m0 + wm * 128 + mf * 16 + quad * 4;
#pragma unroll
        for (int nf = 0; nf < 4; ++nf) {
            const int col = n0 + wn * 64 + nf * 16 + l15;
            if (col < M) {
#pragma unroll
                for (int r = 0; r < 4; ++r) {
                    const int row = row0 + r;
                    if (row < M) {
                        const float v = acc[mf][nf][r];
                        C[(long)row * M + col] = v;
                        if (mirror) C[(long)col * M + row] = v;
                    }
                }
            }
        }
    }
}

// ---------------- f32 -> bf16 cast (vectorized) ----------------
__global__ __launch_bounds__(256) void cast_f32_bf16_k(const float* __restrict__ in,
                                                       bf16* __restrict__ out, long n) {
    long i = ((long)blockIdx.x * 256 + threadIdx.x) * 4;
    if (i >= n) return;
    float4 v = *(const float4*)(in + i);
    bf16x4 o;
    o[0] = (bf16)v.x; o[1] = (bf16)v.y; o[2] = (bf16)v.z; o[3] = (bf16)v.w;
    *(bf16x4*)(out + i) = o;
}

__global__ __launch_bounds__(256) void cast4_f32_bf16_k(const float* __restrict__ a,
                                                        const float* __restrict__ b,
                                                        const float* __restrict__ c,
                                                        const float* __restrict__ d,
                                                        bf16* __restrict__ out, long n) {
    const int w = blockIdx.y;
    const float* in = (w == 0) ? a : (w == 1) ? b : (w == 2) ? c : d;
    bf16* o = out + (long)w * n;
    long i = ((long)blockIdx.x * 256 + threadIdx.x) * 4;
    if (i >= n) return;
    float4 v = *(const float4*)(in + i);
    bf16x4 ov;
    ov[0] = (bf16)v.x; ov[1] = (bf16)v.y; ov[2] = (bf16)v.z; ov[3] = (bf16)v.w;
    *(bf16x4*)(o + i) = ov;
}

// ---------------- bf16 tiled transpose with K-pad (batched) ----------------
// out[C][Rpad]; rows gr in [R, Rpad) written as 0 (zero K-pad for the GEMM)
__global__ __launch_bounds__(256) void transpose_pad_bf16_k(const bf16* __restrict__ in,
                                                            bf16* __restrict__ out,
                                                            int R, int C, int Rpad,
                                                            long sIn, long sOut) {
    __shared__ bf16 tile[64][65];
    in += (long)blockIdx.z * sIn;
    out += (long)blockIdx.z * sOut;
    const int r0 = blockIdx.y * 64, c0 = blockIdx.x * 64;
    const int tx = threadIdx.x & 63, ty = threadIdx.x >> 6;
#pragma unroll
    for (int i = 0; i < 16; i++) {
        int r = ty * 16 + i;
        int gr = r0 + r, gc = c0 + tx;
        tile[r][tx] = (gr < R && gc < C) ? in[(long)gr * C + gc] : (bf16)0.f;
    }
    __syncthreads();
#pragma unroll
    for (int i = 0; i < 16; i++) {
        int c = ty * 16 + i;
        int gc = c0 + c, gr = r0 + tx;
        if (gc < C && gr < Rpad) out[(long)gc * Rpad + gr] = tile[tx][c];
    }
}

// ---------------- adjacency: column sums of s^2 (partials + combine) ----------------
__global__ __launch_bounds__(256) void colsum_part_k(const float* __restrict__ s,
                                                     float* __restrict__ part) {
    int m = blockIdx.x * 256 + threadIdx.x;
    if (m >= N_NODES) return;
    int y = blockIdx.y, b = blockIdx.z;
    const float* sb = s + (long)b * N_NODES * N_NODES;
    float acc = 0.f;
    for (int n = y * 196; n < y * 196 + 196; ++n) {
        float v = sb[(long)n * N_NODES + m];
        acc += v * v;
    }
    part[((long)y * 4 + b) * N_NODES + m] = acc;
}

__global__ __launch_bounds__(256) void colsum_comb_k(const float* __restrict__ part,
                                                     float* __restrict__ inv) {
    int m = blockIdx.x * 256 + threadIdx.x;
    if (m >= N_NODES) return;
    int b = blockIdx.y;
    float a = 0.f;
#pragma unroll
    for (int y = 0; y < 8; y++) a += part[((long)y * 4 + b) * N_NODES + m];
    inv[(long)b * N_NODES + m] = 1.0f / a;
}

// lap[n,m] = 0.5*s^2[n,m]*inv[m] + 0.5*(n==m); row stride LAP_K, zero K-pad
__global__ __launch_bounds__(256) void lap_build_k(const float* __restrict__ s,
                                                   const float* __restrict__ inv,
                                                   bf16* __restrict__ lap) {
    int m = blockIdx.x * 256 + threadIdx.x;
    if (m >= LAP_K) return;
    int n = blockIdx.y, b = blockIdx.z;
    long off = (long)b * N_NODES * LAP_K + (long)n * LAP_K + m;
    if (m >= N_NODES) { lap[off] = (bf16)0.f; return; }
    float v = s[(long)b * N_NODES * N_NODES + (long)n * N_NODES + m];
    float l = 0.5f * v * v * inv[(long)b * N_NODES + m];
    if (n == m) l += 0.5f;
    lap[off] = (bf16)l;
}

// ---------------- LayerNorm(2048) + LeakyReLU(0.1), row-per-block ----------------
__global__ __launch_bounds__(256) void ln_leaky_k(const float* __restrict__ y,
                                                  const float* __restrict__ g,
                                                  const float* __restrict__ beta,
                                                  bf16* __restrict__ z) {
    const long row = blockIdx.x;
    const float* yr = y + row * CDIM;
    const int t = threadIdx.x;
    float v[8];
    float s = 0.f, ss = 0.f;
#pragma unroll
    for (int i = 0; i < 8; i++) {
        float x = yr[t + 256 * i];
        v[i] = x; s += x; ss += x * x;
    }
#pragma unroll
    for (int o = 32; o > 0; o >>= 1) {
        s += __shfl_down(s, o);
        ss += __shfl_down(ss, o);
    }
    __shared__ float sh[8];
    const int wave = t >> 6;
    if ((t & 63) == 0) { sh[wave] = s; sh[wave + 4] = ss; }
    __syncthreads();
    if (t == 0) {
        float a = 0.f, b2 = 0.f;
#pragma unroll
        for (int w = 0; w < 4; w++) { a += sh[w]; b2 += sh[w + 4]; }
        sh[0] = a; sh[4] = b2;
    }
    __syncthreads();
    const float mean = sh[0] * (1.f / 2048.f);
    const float var = sh[4] * (1.f / 2048.f) - mean * mean;
    const float invs = rsqrtf(var + 1e-5f);
    bf16* zr = z + row * CDIM;
#pragma unroll
    for (int i = 0; i < 8; i++) {
        int c = t + 256 * i;
        float o = (v[i] - mean) * invs * g[c] + beta[c];
        o = o > 0.f ? o : 0.1f * o;
        zr[c] = (bf16)o;
    }
}

// ---------------- head: conv1 over 8 frame channels ----------------
__global__ __launch_bounds__(256) void conv1_k(const bf16* __restrict__ z,
                                               const float* __restrict__ cw,
                                               const float* __restrict__ cb,
                                               bf16* __restrict__ tb) {
    const int b = blockIdx.z, hw = blockIdx.y;
    const int c = blockIdx.x * 256 + threadIdx.x;
    float acc = cb[0];
#pragma unroll
    for (int f = 0; f < 8; f++)
        acc += (float)z[((long)b * N_NODES + f * 196 + hw) * CDIM + c] * cw[f];
    tb[((long)b * 196 + hw) * CDIM + c] = (bf16)acc;
}

// ---------------- bilinear x2 upsample, half-pixel, edge clamp ----------------
__global__ __launch_bounds__(256) void upsample_k(const bf16* __restrict__ tb,
                                                  bf16* __restrict__ u) {
    const int b = blockIdx.z, i = blockIdx.y, j = blockIdx.x;
    const float si = 0.5f * i - 0.25f, sj = 0.5f * j - 0.25f;
    const int i0 = (int)floorf(si), j0 = (int)floorf(sj);
    const float wi = si - i0, wj = sj - j0;
    const int i0c = max(i0, 0), i1c = min(i0 + 1, 13);
    const int j0c = max(j0, 0), j1c = min(j0 + 1, 13);
    const bf16* base = tb + (long)b * 196 * CDIM;
    const long r00 = ((long)i0c * 14 + j0c) * CDIM, r01 = ((long)i0c * 14 + j1c) * CDIM;
    const long r10 = ((long)i1c * 14 + j0c) * CDIM, r11 = ((long)i1c * 14 + j1c) * CDIM;
    bf16* ur = u + ((long)(b * 28 + i) * 28 + j) * CDIM;
    const float w00 = (1.f - wi) * (1.f - wj), w01 = (1.f - wi) * wj;
    const float w10 = wi * (1.f - wj), w11 = wi * wj;
    for (int k = 0; k < 8; k++) {
        int cc = threadIdx.x + 256 * k;
        float v = w00 * (float)base[r00 + cc] + w01 * (float)base[r01 + cc] +
                  w10 * (float)base[r10 + cc] + w11 * (float)base[r11 + cc];
        ur[cc] = (bf16)v;
    }
}

// ---------------- deconv weight transform ----------------
__global__ __launch_bounds__(256) void wt_k(const float* __restrict__ dw,
                                            bf16* __restrict__ Wt) {
    const int ic = blockIdx.x * 256 + threadIdx.x;
    const int oc = blockIdx.y;
    const float* src = dw + ((long)ic * 1024 + oc) * 9;
#pragma unroll
    for (int r = 0; r < 3; r++)
#pragma unroll
        for (int s = 0; s < 3; s++) {
            int kh = 2 - r, kw = 2 - s;
            Wt[((long)(kh * 3 + kw) * 1024 + oc) * 2048 + ic] = (bf16)src[r * 3 + s];
        }
}

// ---------------- deconv scatter ----------------
__global__ __launch_bounds__(256) void deconv_scatter_k(const bf16* __restrict__ r,
                                                        const float* __restrict__ db,
                                                        float* __restrict__ out) {
    const int blk = blockIdx.x;          // 4096 = b*1024 + oc
    const int b = blk >> 10, oc = blk & 1023;
    const float bias = db[oc];
    float* ob = out + (long)blk * 82 * 82;
    for (int e = threadIdx.x; e < 82 * 82; e += 256) {
        const int oh = e / 82, ow = e - oh * 82;
        const int mh = oh % 3, mw = ow % 3;
        const int kh = (mh == 0) ? 1 : ((mh == 1) ? 0 : 2);
        const int kw = (mw == 0) ? 1 : ((mw == 1) ? 0 : 2);
        const int ih = (oh - (1 - kh)) / 3;
        const int iw = (ow - (1 - kw)) / 3;
        const int g = kh * 3 + kw;
        ob[e] = (float)r[(long)(g * 1024 + oc) * 3136 + b * 784 + ih * 28 + iw] + bias;
    }
}

// =====================================================================
extern "C" void kernel_launch(void* const* d_in, const int* in_sizes, int n_in,
                              void* d_out, int out_size, void* d_ws, size_t ws_size,
                              hipStream_t stream) {
    const float* x        = (const float*)d_in[0];
    const float* w_fc1    = (const float*)d_in[1];
    const float* w1       = (const float*)d_in[2];
    const float* g1       = (const float*)d_in[3];
    const float* b1       = (const float*)d_in[4];
    const float* w2       = (const float*)d_in[5];
    const float* g2       = (const float*)d_in[6];
    const float* b2       = (const float*)d_in[7];
    const float* w3       = (const float*)d_in[8];
    const float* g3       = (const float*)d_in[9];
    const float* b3       = (const float*)d_in[10];
    const float* conv1_w  = (const float*)d_in[11];
    const float* conv1_b  = (const float*)d_in[12];
    const float* deconv_w = (const float*)d_in[13];
    const float* deconv_b = (const float*)d_in[14];
    float* out = (float*)d_out;

    // ---- workspace layout (bytes) ----
    char* W = (char*)d_ws;
    bf16* wb   = (bf16*)(W + 0);            // 4 x 2048x2048 bf16 = 33,554,432
    bf16* xb   = (bf16*)(W + 33554432);     // 6272x2048 bf16 (later: z)
    bf16* xbT  = (bf16*)(W + 59244544);     // 4 x 2048x1664 bf16 = 27,262,976 (K-pad)
    bf16* hb   = (bf16*)(W + 86507520);     // 6272x2048 bf16 (later: outN)
    bf16* lap  = (bf16*)(W + 112197632);    // 4 x 1568x1664 bf16 = 20,873,216
    bf16* tbuf = (bf16*)(W + 133070848);    // 4 x 196x2048 bf16 = 3,211,264
    bf16* ubuf = (bf16*)(W + 136282112);    // 4 x 784x2048 bf16 = 12,845,056
    bf16* Wt   = (bf16*)(W + 149127168);    // 9 x 1024x2048 bf16 = 37,748,736
    float* ybuf = (float*)(W + 186875904);  // 6272x2048 f32 = 51,380,224
    float* sbuf = (float*)(W + 186875904);  // s overlays y (dead before first y write)
    float* part = (float*)(W + 238256128);  // 8x4x1568 f32
    float* invc = (float*)(W + 238456832);  // 4x1568 f32
    bf16* rbuf = (bf16*)(W + 0);            // 9216x3136 bf16 = 57,802,752 (overlay wb/xb)
    bf16* zb = xb;
    bf16* zT = xbT;
    bf16* outN = hb;

    const long WMAT = (long)2048 * 2048;
    bf16* wb0 = wb, *wb1 = wb + WMAT, *wb2 = wb + 2 * WMAT, *wb3 = wb + 3 * WMAT;

    // ---- weight / input casts ----
    cast4_f32_bf16_k<<<dim3(4096, 4), 256, 0, stream>>>(w_fc1, w1, w2, w3, wb, WMAT);
    cast_f32_bf16_k<<<dim3(12544), 256, 0, stream>>>(x, xb, (long)6272 * 2048);
    wt_k<<<dim3(8, 1024), 256, 0, stream>>>(deconv_w, Wt);

    // xbT = per-batch transpose of xb: [1568,2048] -> [2048,1664] (zero pad)
    transpose_pad_bf16_k<<<dim3(32, 26, 4), 256, 0, stream>>>(
        xb, xbT, N_NODES, CDIM, LAP_K, (long)N_NODES * CDIM, (long)CDIM * LAP_K);

    // ---- h = x @ w_fc1^T  (M=6272,N=2048,K=2048) ----
    gemm256_nt<bf16><<<dim3(25, 8, 1), 512, 0, stream>>>(
        xb, wb0, hb, 6272, 2048, 2048, 0, 0, 0);

    // ---- s = h h^T per batch (28 upper-tri 256-tiles, mirrored) ----
    gemm256_sym<<<dim3(28, 1, 4), 512, 0, stream>>>(
        hb, sbuf, N_NODES, 2048,
        (long)N_NODES * 2048, (long)N_NODES * N_NODES);

    // ---- lap = 0.5*s^2/colsum + 0.5*I (row stride 1664, zero pad) ----
    colsum_part_k<<<dim3(7, 8, 4), 256, 0, stream>>>(sbuf, part);
    colsum_comb_k<<<dim3(7, 4), 256, 0, stream>>>(part, invc);
    lap_build_k<<<dim3(7, N_NODES, 4), 256, 0, stream>>>(sbuf, invc, lap);

    // ---- 3x (lap matmul -> linear -> LN+leaky) ----
    const bf16* wlayer[3] = {wb1, wb2, wb3};
    const float* gl[3] = {g1, g2, g3};
    const float* bl[3] = {b1, b2, b3};
    for (int i = 0; i < 3; i++) {
        const bf16* prevT = (i == 0) ? xbT : zT;
        // outN = lap @ prev: M=1568, N=2048, K=1664 (zero-padded), batched
        gemm256_nt<bf16><<<dim3(7, 8, 4), 512, 0, stream>>>(
            lap, prevT, outN, N_NODES, CDIM, LAP_K,
            (long)N_NODES * LAP_K, (long)CDIM * LAP_K, (long)N_NODES * CDIM);
        // y = outN @ w^T  (M=6272, N=2048, K=2048), f32 out
        gemm256_nt<float><<<dim3(25, 8, 1), 512, 0, stream>>>(
            outN, wlayer[i], ybuf, 6272, 2048, 2048, 0, 0, 0);
        ln_leaky_k<<<dim3(6272), 256, 0, stream>>>(ybuf, gl[i], bl[i], zb);
        if (i < 2) {
            transpose_pad_bf16_k<<<dim3(32, 26, 4), 256, 0, stream>>>(
                zb, zT, N_NODES, CDIM, LAP_K, (long)N_NODES * CDIM, (long)CDIM * LAP_K);
        }
    }

    // ---- head ----
    conv1_k<<<dim3(8, 196, 4), 256, 0, stream>>>(zb, conv1_w, conv1_b, tbuf);
    upsample_k<<<dim3(28, 28, 4), 256, 0, stream>>>(tbuf, ubuf);
    // deconv GEMM (M=9216, N=3136, K=2048)
    gemm256_nt<bf16><<<dim3(36, 13, 1), 512, 0, stream>>>(
        Wt, ubuf, rbuf, 9216, 3136, 2048, 0, 0, 0);
    deconv_scatter_k<<<dim3(4096), 256, 0, stream>>>(rbuf, deconv_b, out);

    (void)in_sizes; (void)n_in; (void)out_size; (void)ws_size;
}